// Round 10
// baseline (530.765 us; speedup 1.0000x reference)
//
#include <hip/hip_runtime.h>
#include <hip/hip_bf16.h>

#define NN 9216      // W*H
#define CCH 256      // channels
#define CTS 268      // castT LDS row stride (u16)

typedef unsigned short u16;
typedef unsigned int   u32;
typedef __attribute__((ext_vector_type(8))) short bf16x8;   // 8 bf16 = 4 VGPRs
typedef __attribute__((ext_vector_type(4))) float f32x4;

static __device__ __forceinline__ u16 f2bf(float f){
    u32 u = __builtin_bit_cast(u32, f);
    u += 0x7fffu + ((u >> 16) & 1u);   // RNE; inputs finite
    return (u16)(u >> 16);
}
static __device__ __forceinline__ float bf2f(u16 h){
    u32 u = ((u32)h) << 16;
    return __builtin_bit_cast(float, u);
}

// ---------------- K0: cast+transpose x,sf -> [n][c] bf16; cast W's ----------
extern "C" __global__ __launch_bounds__(256)
void castT(const float* __restrict__ x, const float* __restrict__ sf,
           const float* __restrict__ Wq, const float* __restrict__ Wk,
           const float* __restrict__ Wv,
           u16* __restrict__ xT, u16* __restrict__ sfT,
           u16* __restrict__ wqb, u16* __restrict__ wkb, u16* __restrict__ wvb,
           float* __restrict__ S2, float* __restrict__ ksum)
{
    const int bid = blockIdx.x, t = threadIdx.x;
    if (bid < 288){
        __shared__ u16 ls[64 * CTS];
        const int isf = bid >= 144;
        const int n0 = (isf ? bid - 144 : bid) * 64;
        const float* src = isf ? sf : x;
        const int nl = t & 63;
        const int cg = t >> 6;          // 0..3
        for (int i = 0; i < 64; ++i){
            int c = cg * 64 + i;
            float v = src[(size_t)c * NN + n0 + nl];
            ls[nl * CTS + c] = f2bf(v);
        }
        __syncthreads();
        u16* dst = (isf ? sfT : xT) + (size_t)(n0 + nl) * 256 + cg * 64;
        const u16* lrow = &ls[nl * CTS + cg * 64];
        #pragma unroll
        for (int j = 0; j < 8; ++j){
            uint2 p = *reinterpret_cast<const uint2*>(lrow + j*8);
            uint2 q = *reinterpret_cast<const uint2*>(lrow + j*8 + 4);
            uint4 o; o.x = p.x; o.y = p.y; o.z = q.x; o.w = q.y;
            *reinterpret_cast<uint4*>(dst + j*8) = o;
        }
    } else {
        const int wb = bid - 288;       // 0..7
        if (wb == 0){
            #pragma unroll
            for (int k2 = 0; k2 < 4; ++k2) S2[t + 256*k2] = 0.f;
            if (t < 32) ksum[t] = 0.f;
        }
        for (int i = 0; i < 40; ++i){
            int idx = wb * 10240 + i * 256 + t;
            if (idx < 8192)        wqb[idx]         = f2bf(Wq[idx]);
            else if (idx < 16384)  wkb[idx - 8192]  = f2bf(Wk[idx - 8192]);
            else                   wvb[idx - 16384] = f2bf(Wv[idx - 16384]);
        }
    }
}

// ---------------- K1: q,k projection via MFMA + center + sumsq --------------
extern "C" __global__ __launch_bounds__(256)
void qk_gemm(const u16* __restrict__ xT, const u16* __restrict__ sfT,
             const u16* __restrict__ wqb, const u16* __restrict__ wkb,
             const float* __restrict__ bq, const float* __restrict__ bk,
             u16* __restrict__ qhb, u16* __restrict__ khb,
             float* __restrict__ pq, float* __restrict__ pk)
{
    __shared__ float wsum[2][2];
    const int bid = blockIdx.x, t = threadIdx.x;
    const int w = t >> 6, l = t & 63, h = l >> 4, r = l & 15;
    const int isk = w >> 1, wn = w & 1;
    const int n0 = bid * 128 + wn * 64;
    const u16* B = isk ? xT : sfT;
    const u16* A = isk ? wkb : wqb;
    const float* bias = isk ? bk : bq;

    f32x4 acc[2][4];
    #pragma unroll
    for (int ot = 0; ot < 2; ++ot)
        #pragma unroll
        for (int nt = 0; nt < 4; ++nt) acc[ot][nt] = (f32x4){0.f,0.f,0.f,0.f};

    for (int ks = 0; ks < 8; ++ks){
        bf16x8 a0 = *reinterpret_cast<const bf16x8*>(A + (r     )*256 + ks*32 + 8*h);
        bf16x8 a1 = *reinterpret_cast<const bf16x8*>(A + (16 + r)*256 + ks*32 + 8*h);
        #pragma unroll
        for (int nt = 0; nt < 4; ++nt){
            bf16x8 b = *reinterpret_cast<const bf16x8*>(
                B + (size_t)(n0 + nt*16 + r)*256 + ks*32 + 8*h);
            acc[0][nt] = __builtin_amdgcn_mfma_f32_16x16x32_bf16(a0, b, acc[0][nt], 0,0,0);
            acc[1][nt] = __builtin_amdgcn_mfma_f32_16x16x32_bf16(a1, b, acc[1][nt], 0,0,0);
        }
    }
    float bs[2][4];
    #pragma unroll
    for (int ot = 0; ot < 2; ++ot)
        #pragma unroll
        for (int g = 0; g < 4; ++g) bs[ot][g] = bias[ot*16 + 4*h + g];

    u16* outb = (isk ? khb : qhb);
    float ssl = 0.f;
    #pragma unroll
    for (int nt = 0; nt < 4; ++nt){
        float loc = 0.f;
        #pragma unroll
        for (int ot = 0; ot < 2; ++ot)
            #pragma unroll
            for (int g = 0; g < 4; ++g){
                acc[ot][nt][g] += bs[ot][g];
                loc += acc[ot][nt][g];
            }
        loc += __shfl_xor(loc, 16);
        loc += __shfl_xor(loc, 32);
        const float mn = loc * (1.f/32.f);
        u16* dstp = outb + (size_t)(n0 + nt*16 + r) * 32;
        #pragma unroll
        for (int ot = 0; ot < 2; ++ot)
            #pragma unroll
            for (int g = 0; g < 4; ++g){
                u16 hb = f2bf(acc[ot][nt][g] - mn);
                float rvx = bf2f(hb);
                ssl = fmaf(rvx, rvx, ssl);
                dstp[ot*16 + 4*h + g] = hb;
            }
    }
    #pragma unroll
    for (int mask = 1; mask <= 32; mask <<= 1) ssl += __shfl_xor(ssl, mask);
    if (l == 0) wsum[isk][wn] = ssl;
    __syncthreads();
    if (t == 0) pq[bid] = wsum[0][0] + wsum[0][1];
    if (t == 1) pk[bid] = wsum[1][0] + wsum[1][1];
}

// ---------------- K2: v projection via MFMA -> vb bf16 [c][m] ---------------
extern "C" __global__ __launch_bounds__(256)
void v_gemm(const u16* __restrict__ xT, const u16* __restrict__ wvb,
            const float* __restrict__ bv, u16* __restrict__ vb)
{
    const int bid = blockIdx.x, t = threadIdx.x;
    const int w = t >> 6, l = t & 63, h = l >> 4, r = l & 15;
    const int m0 = (bid >> 2) * 64, c0 = (bid & 3) * 64;

    f32x4 acc[4];
    #pragma unroll
    for (int nt = 0; nt < 4; ++nt) acc[nt] = (f32x4){0.f,0.f,0.f,0.f};

    for (int ks = 0; ks < 8; ++ks){
        bf16x8 a = *reinterpret_cast<const bf16x8*>(wvb + (c0 + w*16 + r)*256 + ks*32 + 8*h);
        #pragma unroll
        for (int nt = 0; nt < 4; ++nt){
            bf16x8 b = *reinterpret_cast<const bf16x8*>(
                xT + (size_t)(m0 + nt*16 + r)*256 + ks*32 + 8*h);
            acc[nt] = __builtin_amdgcn_mfma_f32_16x16x32_bf16(a, b, acc[nt], 0,0,0);
        }
    }
    float bvv[4];
    #pragma unroll
    for (int g = 0; g < 4; ++g) bvv[g] = bv[c0 + w*16 + 4*h + g];
    #pragma unroll
    for (int nt = 0; nt < 4; ++nt)
        #pragma unroll
        for (int g = 0; g < 4; ++g)
            vb[(size_t)(c0 + w*16 + 4*h + g) * NN + m0 + nt*16 + r] =
                f2bf(acc[nt][g] + bvv[g]);
}

// ---------------- K3: S2 = K̂ᵀK̂ and ksum = Σ k̂ ----------------
extern "C" __global__ __launch_bounds__(256)
void s2k(const u16* __restrict__ khb, float* __restrict__ S2,
         float* __restrict__ ksum)
{
    __shared__ float ks[36][33];
    const int t = threadIdx.x;
    const int m0 = blockIdx.x * 36;
    if (t < 144){
        const int row = t >> 2, seg = (t & 3) * 8;
        bf16x8 v = *reinterpret_cast<const bf16x8*>(khb + (m0 + row) * 32 + seg);
        #pragma unroll
        for (int j = 0; j < 8; ++j)
            ks[row][seg + j] = bf2f((u16)v[j]);
    }
    __syncthreads();
    #pragma unroll
    for (int k2 = 0; k2 < 4; ++k2){
        const int task = t + 256 * k2;
        const int i = task >> 5, j = task & 31;
        float s = 0.f;
        for (int m = 0; m < 36; ++m)
            s = fmaf(ks[m][i], ks[m][j], s);
        atomicAdd(S2 + task, s);
    }
    if (t < 32){
        float s = 0.f;
        for (int m = 0; m < 36; ++m) s += ks[m][t];
        atomicAdd(ksum + t, s);
    }
}

// ---------------- K4: per-row Taylor rowsum -> rinv ----------------
extern "C" __global__ __launch_bounds__(256)
void rowfin(const u16* __restrict__ qhb, const float* __restrict__ S2,
            const float* __restrict__ ksum,
            const float* __restrict__ pq, const float* __restrict__ pk,
            float* __restrict__ rinv_arr)
{
    __shared__ float s2s[1024];
    __shared__ float kss[32];
    const int t = threadIdx.x;
    #pragma unroll
    for (int k2 = 0; k2 < 4; ++k2) s2s[t + 256*k2] = S2[t + 256*k2];
    if (t < 32) kss[t] = ksum[t];
    __syncthreads();

    float sq = 0.f, sk = 0.f;
    for (int i = 0; i < 72; ++i){ sq += pq[i]; sk += pk[i]; }
    const float d = rsqrtf(sq) * rsqrtf(sk);

    const int n = blockIdx.x * 256 + t;
    float q[32];
    #pragma unroll
    for (int s8 = 0; s8 < 4; ++s8){
        bf16x8 v = *reinterpret_cast<const bf16x8*>(qhb + n * 32 + s8 * 8);
        #pragma unroll
        for (int j = 0; j < 8; ++j) q[s8*8 + j] = bf2f((u16)v[j]);
    }
    float d1 = 0.f;
    #pragma unroll
    for (int o = 0; o < 32; ++o) d1 = fmaf(q[o], kss[o], d1);
    float quad = 0.f;
    for (int o = 0; o < 32; ++o){
        float s = 0.f;
        #pragma unroll
        for (int j = 0; j < 32; ++j) s = fmaf(s2s[o*32 + j], q[j], s);
        quad = fmaf(q[o], s, quad);
    }
    const float rs = 9216.f + d1 * d + 0.5f * quad * d * d;
    rinv_arr[n] = 1.f / rs;
}

// ---------------- K5: barrier-free per-wave attention + PV ----------------
// grid 4608 x 64 threads. ms = bid&7 (XCD-pinned), ng = bid>>3 (0..575).
// Wave owns 16 n-rows x 1152 m-cols. Swapped QK -> direct reg store of
// attention; PV fragments via 2KB wave-private LDS (no __syncthreads at all).
extern "C" __global__ __launch_bounds__(64, 4)
void attn_main(const u16* __restrict__ qhb, const u16* __restrict__ khb,
               const u16* __restrict__ vb,
               const float* __restrict__ pq, const float* __restrict__ pk,
               const float* __restrict__ rinv_arr,
               float* __restrict__ outdst, float* __restrict__ attnf,
               int use_atomic)
{
    __shared__ u16 pws[2][64 * 8];   // [k-window][slot(64) x 8 u16] = 2KB
    const int bid = blockIdx.x, l = threadIdx.x;
    const int h = l >> 4, r = l & 15;
    const int ms = bid & 7, ng = bid >> 3;
    const int n0 = ng * 16, mbase = ms * 1152;

    float sq = 0.f, sk = 0.f;
    for (int i = 0; i < 72; ++i){ sq += pq[i]; sk += pk[i]; }
    const float inv_den = rsqrtf(sq) * rsqrtf(sk);
    const float rv = rinv_arr[n0 + r];

    const bf16x8 qf = *reinterpret_cast<const bf16x8*>(qhb + (size_t)(n0 + r)*32 + 8*h);

    // acc[ct][g] = D[n = n0+4h+g][c = ct*16+r]
    f32x4 acc[16];
    #pragma unroll
    for (int ct = 0; ct < 16; ++ct) acc[ct] = (f32x4){0.f,0.f,0.f,0.f};

    for (int c = 0; c < 18; ++c){
        const int m0c = mbase + c * 64;
        // 4 m-tiles: swapped QK -> Taylor -> direct attn store + LDS fragment stage
        #pragma unroll
        for (int k64 = 0; k64 < 4; ++k64){
            bf16x8 kf = *reinterpret_cast<const bf16x8*>(
                khb + (size_t)(m0c + k64*16 + r)*32 + 8*h);
            f32x4 z = {0.f,0.f,0.f,0.f};
            // e[g] = E[m = m0c+16*k64+4h+g][n = n0+r]
            f32x4 e = __builtin_amdgcn_mfma_f32_16x16x32_bf16(kf, qf, z, 0,0,0);
            f32x4 p;
            #pragma unroll
            for (int g = 0; g < 4; ++g){
                float ep = e[g] * inv_den;
                p[g] = fmaf(ep, fmaf(0.5f, ep, 1.f), 1.f) * rv;   // normalized P
            }
            __builtin_nontemporal_store(p, reinterpret_cast<f32x4*>(
                attnf + (size_t)(n0 + r) * NN + m0c + k64*16 + 4*h));
            // stage into PV A-fragment layout: slot (hp*16+r), half (h&1)
            uint2 uu;
            uu.x = (u32)f2bf(p[0]) | ((u32)f2bf(p[1]) << 16);
            uu.y = (u32)f2bf(p[2]) | ((u32)f2bf(p[3]) << 16);
            const int W  = k64 >> 1;
            const int hp = (k64 & 1) * 2 + (h >> 1);
            *reinterpret_cast<uint2*>(&pws[W][(hp*16 + r)*8 + (h & 1)*4]) = uu;
        }
        // PV: per 32-m window, A = staged P fragment (lane-linear b128 read)
        #pragma unroll
        for (int W = 0; W < 2; ++W){
            bf16x8 pa = *reinterpret_cast<const bf16x8*>(&pws[W][l * 8]);
            #pragma unroll
            for (int ct = 0; ct < 16; ++ct){
                bf16x8 av = *reinterpret_cast<const bf16x8*>(
                    vb + (size_t)(ct*16 + r) * NN + m0c + W*32 + 8*h);
                acc[ct] = __builtin_amdgcn_mfma_f32_16x16x32_bf16(pa, av, acc[ct], 0,0,0);
            }
        }
    }

    if (!use_atomic){
        float* dst = outdst + (size_t)ms * (CCH * NN);
        #pragma unroll
        for (int ct = 0; ct < 16; ++ct)
            *reinterpret_cast<f32x4*>(dst + (size_t)(ct*16 + r) * NN + n0 + 4*h) = acc[ct];
    } else {
        #pragma unroll
        for (int ct = 0; ct < 16; ++ct)
            #pragma unroll
            for (int g = 0; g < 4; ++g)
                atomicAdd(outdst + (size_t)(ct*16 + r) * NN + n0 + 4*h + g, acc[ct][g]);
    }
}

// ---------------- K6: out = gamma*(sum partials) + x ----------------
extern "C" __global__ __launch_bounds__(256)
void epilogue(const float* __restrict__ x, const float* __restrict__ gm,
              const float* __restrict__ parts, int nparts,
              float* __restrict__ outf)
{
    const float g = gm[0];
    const size_t i = ((size_t)blockIdx.x * 256 + threadIdx.x) * 4;
    float4 a;
    if (nparts > 0){
        a.x = a.y = a.z = a.w = 0.f;
        for (int s = 0; s < nparts; ++s){
            float4 p = *reinterpret_cast<const float4*>(parts + (size_t)s * (CCH*NN) + i);
            a.x += p.x; a.y += p.y; a.z += p.z; a.w += p.w;
        }
    } else {
        a = *reinterpret_cast<float4*>(outf + i);
    }
    float4 xv = *reinterpret_cast<const float4*>(x + i);
    a.x = fmaf(g, a.x, xv.x);
    a.y = fmaf(g, a.y, xv.y);
    a.z = fmaf(g, a.z, xv.z);
    a.w = fmaf(g, a.w, xv.w);
    *reinterpret_cast<float4*>(outf + i) = a;
}

extern "C" __global__ __launch_bounds__(256)
void zero_buf(float* __restrict__ p)
{
    float4 z = {0.f,0.f,0.f,0.f};
    *reinterpret_cast<float4*>(p + ((size_t)blockIdx.x * 256 + threadIdx.x) * 4) = z;
}

extern "C" void kernel_launch(void* const* d_in, const int* in_sizes, int n_in,
                              void* d_out, int out_size, void* d_ws, size_t ws_size,
                              hipStream_t stream)
{
    (void)in_sizes; (void)n_in; (void)out_size;
    const float* x  = (const float*)d_in[0];
    const float* sf = (const float*)d_in[1];
    const float* Wq = (const float*)d_in[2];
    const float* bq = (const float*)d_in[3];
    const float* Wk = (const float*)d_in[4];
    const float* bk = (const float*)d_in[5];
    const float* Wv = (const float*)d_in[6];
    const float* bv = (const float*)d_in[7];
    const float* gm = (const float*)d_in[8];

    float* outf  = (float*)d_out;                       // [256][9216] f32
    float* attnf = outf + (size_t)256 * 9216;           // [9216][9216] f32

    char* ws = (char*)d_ws;
    u16*   xT    = (u16*)(ws);                          //  4,718,592
    u16*   sfT   = (u16*)(ws +  4718592);               //  4,718,592
    u16*   wqb   = (u16*)(ws +  9437184);               //     16,384
    u16*   wkb   = (u16*)(ws +  9453568);               //     16,384
    u16*   wvb   = (u16*)(ws +  9469952);               //    131,072
    u16*   qhb   = (u16*)(ws +  9601024);               //    589,824
    u16*   khb   = (u16*)(ws + 10190848);               //    589,824
    u16*   vbp   = (u16*)(ws + 10780672);               //  4,718,592
    float* pq    = (float*)(ws + 15499264);             //        288
    float* pk    = (float*)(ws + 15499552);             //        288
    float* S2    = (float*)(ws + 15499840);             //      4,096
    float* ksum  = (float*)(ws + 15503936);             //        128
    float* rinv  = (float*)(ws + 15504064);             //     36,864
    float* parts = (float*)(ws + 15540928);             // 8 × 9,437,184
    const size_t need = 15540928ull + 8ull * 9437184ull;

    const bool use_parts = (ws_size >= need);

    castT   <<<dim3(296),  dim3(256), 0, stream>>>(x, sf, Wq, Wk, Wv,
                                                   xT, sfT, wqb, wkb, wvb, S2, ksum);
    qk_gemm <<<dim3(72),   dim3(256), 0, stream>>>(xT, sfT, wqb, wkb, bq, bk,
                                                   qhb, khb, pq, pk);
    v_gemm  <<<dim3(576),  dim3(256), 0, stream>>>(xT, wvb, bv, vbp);
    s2k     <<<dim3(256),  dim3(256), 0, stream>>>(khb, S2, ksum);
    rowfin  <<<dim3(36),   dim3(256), 0, stream>>>(qhb, S2, ksum, pq, pk, rinv);
    if (!use_parts)
        zero_buf<<<dim3(2304), dim3(256), 0, stream>>>(outf);
    attn_main<<<dim3(4608), dim3(64), 0, stream>>>(qhb, khb, vbp, pq, pk, rinv,
                                                   use_parts ? parts : outf, attnf,
                                                   use_parts ? 0 : 1);
    epilogue <<<dim3(2304), dim3(256), 0, stream>>>(x, gm, parts,
                                                    use_parts ? 8 : 0, outf);
}

// Round 11
// 211.149 us; speedup vs baseline: 2.5137x; 2.5137x over previous
//
#include <hip/hip_runtime.h>
#include <hip/hip_bf16.h>

#define NN 9216      // W*H
#define CCH 256      // channels
#define PS2 268      // attn ps row stride (u16): dw stride 134 — conflict-free measured
#define CTS 268      // castT LDS row stride (u16)

typedef unsigned short u16;
typedef unsigned int   u32;
typedef __attribute__((ext_vector_type(8))) short bf16x8;   // 8 bf16 = 4 VGPRs
typedef __attribute__((ext_vector_type(4))) float f32x4;

static __device__ __forceinline__ u16 f2bf(float f){
    u32 u = __builtin_bit_cast(u32, f);
    u += 0x7fffu + ((u >> 16) & 1u);   // RNE; inputs finite
    return (u16)(u >> 16);
}
static __device__ __forceinline__ float bf2f(u16 h){
    u32 u = ((u32)h) << 16;
    return __builtin_bit_cast(float, u);
}

// LDS-only barrier: order LDS ops, but DON'T drain global stores (vmcnt)
#define BAR_LDS() do { \
    asm volatile("s_waitcnt lgkmcnt(0)" ::: "memory"); \
    __builtin_amdgcn_s_barrier(); \
} while (0)

// ---------------- K0: cast+transpose x,sf -> [n][c] bf16; cast W's ----------
extern "C" __global__ __launch_bounds__(256)
void castT(const float* __restrict__ x, const float* __restrict__ sf,
           const float* __restrict__ Wq, const float* __restrict__ Wk,
           const float* __restrict__ Wv,
           u16* __restrict__ xT, u16* __restrict__ sfT,
           u16* __restrict__ wqb, u16* __restrict__ wkb, u16* __restrict__ wvb,
           float* __restrict__ S2, float* __restrict__ ksum)
{
    const int bid = blockIdx.x, t = threadIdx.x;
    if (bid < 288){
        __shared__ u16 ls[64 * CTS];
        const int isf = bid >= 144;
        const int n0 = (isf ? bid - 144 : bid) * 64;
        const float* src = isf ? sf : x;
        const int nl = t & 63;
        const int cg = t >> 6;          // 0..3
        for (int i = 0; i < 64; ++i){
            int c = cg * 64 + i;
            float v = src[(size_t)c * NN + n0 + nl];
            ls[nl * CTS + c] = f2bf(v);
        }
        __syncthreads();
        u16* dst = (isf ? sfT : xT) + (size_t)(n0 + nl) * 256 + cg * 64;
        const u16* lrow = &ls[nl * CTS + cg * 64];
        #pragma unroll
        for (int j = 0; j < 8; ++j){
            uint2 p = *reinterpret_cast<const uint2*>(lrow + j*8);
            uint2 q = *reinterpret_cast<const uint2*>(lrow + j*8 + 4);
            uint4 o; o.x = p.x; o.y = p.y; o.z = q.x; o.w = q.y;
            *reinterpret_cast<uint4*>(dst + j*8) = o;
        }
    } else {
        const int wb = bid - 288;       // 0..7
        if (wb == 0){
            #pragma unroll
            for (int k2 = 0; k2 < 4; ++k2) S2[t + 256*k2] = 0.f;
            if (t < 32) ksum[t] = 0.f;
        }
        for (int i = 0; i < 40; ++i){
            int idx = wb * 10240 + i * 256 + t;
            if (idx < 8192)        wqb[idx]         = f2bf(Wq[idx]);
            else if (idx < 16384)  wkb[idx - 8192]  = f2bf(Wk[idx - 8192]);
            else                   wvb[idx - 16384] = f2bf(Wv[idx - 16384]);
        }
    }
}

// ---------------- K1: q,k projection via MFMA + center + sumsq --------------
extern "C" __global__ __launch_bounds__(256)
void qk_gemm(const u16* __restrict__ xT, const u16* __restrict__ sfT,
             const u16* __restrict__ wqb, const u16* __restrict__ wkb,
             const float* __restrict__ bq, const float* __restrict__ bk,
             u16* __restrict__ qhb, u16* __restrict__ khb,
             float* __restrict__ pq, float* __restrict__ pk)
{
    __shared__ float wsum[2][2];
    const int bid = blockIdx.x, t = threadIdx.x;
    const int w = t >> 6, l = t & 63, h = l >> 4, r = l & 15;
    const int isk = w >> 1, wn = w & 1;
    const int n0 = bid * 128 + wn * 64;
    const u16* B = isk ? xT : sfT;
    const u16* A = isk ? wkb : wqb;
    const float* bias = isk ? bk : bq;

    f32x4 acc[2][4];
    #pragma unroll
    for (int ot = 0; ot < 2; ++ot)
        #pragma unroll
        for (int nt = 0; nt < 4; ++nt) acc[ot][nt] = (f32x4){0.f,0.f,0.f,0.f};

    for (int ks = 0; ks < 8; ++ks){
        bf16x8 a0 = *reinterpret_cast<const bf16x8*>(A + (r     )*256 + ks*32 + 8*h);
        bf16x8 a1 = *reinterpret_cast<const bf16x8*>(A + (16 + r)*256 + ks*32 + 8*h);
        #pragma unroll
        for (int nt = 0; nt < 4; ++nt){
            bf16x8 b = *reinterpret_cast<const bf16x8*>(
                B + (size_t)(n0 + nt*16 + r)*256 + ks*32 + 8*h);
            acc[0][nt] = __builtin_amdgcn_mfma_f32_16x16x32_bf16(a0, b, acc[0][nt], 0,0,0);
            acc[1][nt] = __builtin_amdgcn_mfma_f32_16x16x32_bf16(a1, b, acc[1][nt], 0,0,0);
        }
    }
    float bs[2][4];
    #pragma unroll
    for (int ot = 0; ot < 2; ++ot)
        #pragma unroll
        for (int g = 0; g < 4; ++g) bs[ot][g] = bias[ot*16 + 4*h + g];

    u16* outb = (isk ? khb : qhb);
    float ssl = 0.f;
    #pragma unroll
    for (int nt = 0; nt < 4; ++nt){
        float loc = 0.f;
        #pragma unroll
        for (int ot = 0; ot < 2; ++ot)
            #pragma unroll
            for (int g = 0; g < 4; ++g){
                acc[ot][nt][g] += bs[ot][g];
                loc += acc[ot][nt][g];
            }
        loc += __shfl_xor(loc, 16);
        loc += __shfl_xor(loc, 32);
        const float mn = loc * (1.f/32.f);
        u16* dstp = outb + (size_t)(n0 + nt*16 + r) * 32;
        #pragma unroll
        for (int ot = 0; ot < 2; ++ot)
            #pragma unroll
            for (int g = 0; g < 4; ++g){
                u16 hb = f2bf(acc[ot][nt][g] - mn);
                float rv = bf2f(hb);
                ssl = fmaf(rv, rv, ssl);
                dstp[ot*16 + 4*h + g] = hb;
            }
    }
    #pragma unroll
    for (int mask = 1; mask <= 32; mask <<= 1) ssl += __shfl_xor(ssl, mask);
    if (l == 0) wsum[isk][wn] = ssl;
    __syncthreads();
    if (t == 0) pq[bid] = wsum[0][0] + wsum[0][1];
    if (t == 1) pk[bid] = wsum[1][0] + wsum[1][1];
}

// ---------------- K2: v projection via MFMA -> vb bf16 [c][m] ---------------
extern "C" __global__ __launch_bounds__(256)
void v_gemm(const u16* __restrict__ xT, const u16* __restrict__ wvb,
            const float* __restrict__ bv, u16* __restrict__ vb)
{
    const int bid = blockIdx.x, t = threadIdx.x;
    const int w = t >> 6, l = t & 63, h = l >> 4, r = l & 15;
    const int m0 = (bid >> 2) * 64, c0 = (bid & 3) * 64;

    f32x4 acc[4];
    #pragma unroll
    for (int nt = 0; nt < 4; ++nt) acc[nt] = (f32x4){0.f,0.f,0.f,0.f};

    for (int ks = 0; ks < 8; ++ks){
        bf16x8 a = *reinterpret_cast<const bf16x8*>(wvb + (c0 + w*16 + r)*256 + ks*32 + 8*h);
        #pragma unroll
        for (int nt = 0; nt < 4; ++nt){
            bf16x8 b = *reinterpret_cast<const bf16x8*>(
                xT + (size_t)(m0 + nt*16 + r)*256 + ks*32 + 8*h);
            acc[nt] = __builtin_amdgcn_mfma_f32_16x16x32_bf16(a, b, acc[nt], 0,0,0);
        }
    }
    float bvv[4];
    #pragma unroll
    for (int g = 0; g < 4; ++g) bvv[g] = bv[c0 + w*16 + 4*h + g];
    #pragma unroll
    for (int nt = 0; nt < 4; ++nt)
        #pragma unroll
        for (int g = 0; g < 4; ++g)
            vb[(size_t)(c0 + w*16 + 4*h + g) * NN + m0 + nt*16 + r] =
                f2bf(acc[nt][g] + bvv[g]);
}

// ---------------- K3: S2 = K̂ᵀK̂ and ksum = Σ k̂ ----------------
extern "C" __global__ __launch_bounds__(256)
void s2k(const u16* __restrict__ khb, float* __restrict__ S2,
         float* __restrict__ ksum)
{
    __shared__ float ks[36][33];
    const int t = threadIdx.x;
    const int m0 = blockIdx.x * 36;
    if (t < 144){
        const int row = t >> 2, seg = (t & 3) * 8;
        bf16x8 v = *reinterpret_cast<const bf16x8*>(khb + (m0 + row) * 32 + seg);
        #pragma unroll
        for (int j = 0; j < 8; ++j)
            ks[row][seg + j] = bf2f((u16)v[j]);
    }
    __syncthreads();
    #pragma unroll
    for (int k2 = 0; k2 < 4; ++k2){
        const int task = t + 256 * k2;
        const int i = task >> 5, j = task & 31;
        float s = 0.f;
        for (int m = 0; m < 36; ++m)
            s = fmaf(ks[m][i], ks[m][j], s);
        atomicAdd(S2 + task, s);
    }
    if (t < 32){
        float s = 0.f;
        for (int m = 0; m < 36; ++m) s += ks[m][t];
        atomicAdd(ksum + t, s);
    }
}

// ---------------- K4: per-row Taylor rowsum -> rinv ----------------
extern "C" __global__ __launch_bounds__(256)
void rowfin(const u16* __restrict__ qhb, const float* __restrict__ S2,
            const float* __restrict__ ksum,
            const float* __restrict__ pq, const float* __restrict__ pk,
            float* __restrict__ rinv_arr)
{
    __shared__ float s2s[1024];
    __shared__ float kss[32];
    const int t = threadIdx.x;
    #pragma unroll
    for (int k2 = 0; k2 < 4; ++k2) s2s[t + 256*k2] = S2[t + 256*k2];
    if (t < 32) kss[t] = ksum[t];
    __syncthreads();

    float sq = 0.f, sk = 0.f;
    for (int i = 0; i < 72; ++i){ sq += pq[i]; sk += pk[i]; }
    const float d = rsqrtf(sq) * rsqrtf(sk);

    const int n = blockIdx.x * 256 + t;
    float q[32];
    #pragma unroll
    for (int s8 = 0; s8 < 4; ++s8){
        bf16x8 v = *reinterpret_cast<const bf16x8*>(qhb + n * 32 + s8 * 8);
        #pragma unroll
        for (int j = 0; j < 8; ++j) q[s8*8 + j] = bf2f((u16)v[j]);
    }
    float d1 = 0.f;
    #pragma unroll
    for (int o = 0; o < 32; ++o) d1 = fmaf(q[o], kss[o], d1);
    float quad = 0.f;
    for (int o = 0; o < 32; ++o){
        float s = 0.f;
        #pragma unroll
        for (int j = 0; j < 32; ++j) s = fmaf(s2s[o*32 + j], q[j], s);
        quad = fmaf(q[o], s, quad);
    }
    const float rs = 9216.f + d1 * d + 0.5f * quad * d * d;
    rinv_arr[n] = 1.f / rs;
}

// ---------------- K5: fused attention write + PV (round-8 structure,
// LDS-only barriers + cached stores) ----------
// grid 1152: nc = bid>>3 (64 n-rows), ms = bid&7 (1152 m-cols)
// 4 periods of 256 + 1 of 128, constant bounds.
extern "C" __global__ __launch_bounds__(256, 3)
void attn_main(const u16* __restrict__ qhb, const u16* __restrict__ khb,
               const u16* __restrict__ vb,
               const float* __restrict__ pq, const float* __restrict__ pk,
               const float* __restrict__ rinv_arr,
               float* __restrict__ outdst, float* __restrict__ attnf,
               int use_atomic)
{
    __shared__ u16 ps[64 * PS2];
    __shared__ float rsl[64];
    const int bid = blockIdx.x;
    const int nc = bid >> 3, ms = bid & 7;
    const int t = threadIdx.x, w = t >> 6, l = t & 63, h = l >> 4, r = l & 15;
    const int n0 = nc * 64, mbase = ms * 1152;

    float sq = 0.f, sk = 0.f;
    for (int i = 0; i < 72; ++i){ sq += pq[i]; sk += pk[i]; }
    const float inv_den = rsqrtf(sq) * rsqrtf(sk);

    if (t < 64) rsl[t] = rinv_arr[n0 + t];

    bf16x8 qf[4];
    #pragma unroll
    for (int nt = 0; nt < 4; ++nt)
        qf[nt] = *reinterpret_cast<const bf16x8*>(qhb + (size_t)(n0 + nt*16 + r)*32 + 8*h);

    // acc[ct][nt] holds D[n][c]: n = n0+nt*16+4h+g, c = w*64+ct*16+r  (swapped PV)
    f32x4 acc[4][4];
    #pragma unroll
    for (int ct = 0; ct < 4; ++ct)
        #pragma unroll
        for (int nt = 0; nt < 4; ++nt)
            acc[ct][nt] = (f32x4){0.f,0.f,0.f,0.f};

    // QK -> Taylor exp (unnormalized) -> ps[bf16]
    #define STAGE_TILE(M0S, K64) \
        _Pragma("unroll") \
        for (int k64 = 0; k64 < (K64); ++k64){ \
            bf16x8 kf = *reinterpret_cast<const bf16x8*>( \
                khb + (size_t)((M0S) + k64*64 + w*16 + r)*32 + 8*h); \
            _Pragma("unroll") \
            for (int nt = 0; nt < 4; ++nt){ \
                f32x4 z = {0.f,0.f,0.f,0.f}; \
                f32x4 e = __builtin_amdgcn_mfma_f32_16x16x32_bf16(qf[nt], kf, z, 0,0,0); \
                _Pragma("unroll") \
                for (int g = 0; g < 4; ++g){ \
                    float ep = e[g] * inv_den; \
                    float pt = fmaf(ep, fmaf(0.5f, ep, 1.f), 1.f); \
                    ps[(nt*16 + 4*h + g) * PS2 + k64*64 + w*16 + r] = f2bf(pt); \
                } \
            } \
        }

    // attention rows -> global f32 (cached stores — L2 absorbs the stream)
    #define WRITE_TILE(M0S, SPAN) \
        _Pragma("unroll 4") \
        for (int j = 0; j < 16; ++j){ \
            const int row = w + 4*j; \
            const float rv = rsl[row]; \
            if ((SPAN) == 256 || l < 32){ \
                ushort4 u = *reinterpret_cast<const ushort4*>(&ps[row * PS2 + l*4]); \
                f32x4 f4; \
                f4[0] = bf2f(u.x)*rv; f4[1] = bf2f(u.y)*rv; \
                f4[2] = bf2f(u.z)*rv; f4[3] = bf2f(u.w)*rv; \
                *reinterpret_cast<f32x4*>( \
                    attnf + (size_t)(n0 + row) * NN + (M0S) + l*4) = f4; \
            } \
        }

    // PV (swapped): acc += P(rows n) x V(rows c)
    #define PV_TILE(M0S, KSL) \
        _Pragma("unroll 2") \
        for (int ksl = 0; ksl < (KSL); ++ksl){ \
            bf16x8 av[4]; \
            _Pragma("unroll") \
            for (int ct = 0; ct < 4; ++ct) \
                av[ct] = *reinterpret_cast<const bf16x8*>( \
                    vb + (size_t)(w*64 + ct*16 + r) * NN + (M0S) + ksl*32 + 8*h); \
            bf16x8 bv2[4]; \
            _Pragma("unroll") \
            for (int nt = 0; nt < 4; ++nt) \
                bv2[nt] = *reinterpret_cast<const bf16x8*>( \
                    &ps[(nt*16 + r) * PS2 + ksl*32 + 8*h]); \
            __builtin_amdgcn_s_setprio(1); \
            _Pragma("unroll") \
            for (int ct = 0; ct < 4; ++ct) \
                _Pragma("unroll") \
                for (int nt = 0; nt < 4; ++nt) \
                    acc[ct][nt] = __builtin_amdgcn_mfma_f32_16x16x32_bf16( \
                        bv2[nt], av[ct], acc[ct][nt], 0,0,0); \
            __builtin_amdgcn_s_setprio(0); \
        }

    for (int p = 0; p < 4; ++p){
        const int m0 = mbase + p * 256;
        STAGE_TILE(m0, 4)
        BAR_LDS();
        WRITE_TILE(m0, 256)
        PV_TILE(m0, 8)
        BAR_LDS();
    }
    {
        const int m0 = mbase + 1024;
        STAGE_TILE(m0, 2)
        BAR_LDS();
        WRITE_TILE(m0, 128)
        PV_TILE(m0, 4)
        BAR_LDS();
    }
    #undef STAGE_TILE
    #undef WRITE_TILE
    #undef PV_TILE

    if (!use_atomic){
        float* dst = outdst + (size_t)ms * (CCH * NN);
        #pragma unroll
        for (int ct = 0; ct < 4; ++ct)
            #pragma unroll
            for (int nt = 0; nt < 4; ++nt){
                f32x4 o;
                #pragma unroll
                for (int g = 0; g < 4; ++g)
                    o[g] = acc[ct][nt][g] * rsl[nt*16 + 4*h + g];
                *reinterpret_cast<f32x4*>(
                    dst + (size_t)(w*64 + ct*16 + r) * NN + n0 + nt*16 + 4*h) = o;
            }
    } else {
        #pragma unroll
        for (int ct = 0; ct < 4; ++ct)
            #pragma unroll
            for (int nt = 0; nt < 4; ++nt)
                #pragma unroll
                for (int g = 0; g < 4; ++g)
                    atomicAdd(outdst + (size_t)(w*64 + ct*16 + r) * NN + n0 + nt*16 + 4*h + g,
                              acc[ct][nt][g] * rsl[nt*16 + 4*h + g]);
    }
}

// ---------------- K6: out = gamma*(sum partials) + x ----------------
extern "C" __global__ __launch_bounds__(256)
void epilogue(const float* __restrict__ x, const float* __restrict__ gm,
              const float* __restrict__ parts, int nparts,
              float* __restrict__ outf)
{
    const float g = gm[0];
    const size_t i = ((size_t)blockIdx.x * 256 + threadIdx.x) * 4;
    float4 a;
    if (nparts > 0){
        a.x = a.y = a.z = a.w = 0.f;
        for (int s = 0; s < nparts; ++s){
            float4 p = *reinterpret_cast<const float4*>(parts + (size_t)s * (CCH*NN) + i);
            a.x += p.x; a.y += p.y; a.z += p.z; a.w += p.w;
        }
    } else {
        a = *reinterpret_cast<float4*>(outf + i);
    }
    float4 xv = *reinterpret_cast<const float4*>(x + i);
    a.x = fmaf(g, a.x, xv.x);
    a.y = fmaf(g, a.y, xv.y);
    a.z = fmaf(g, a.z, xv.z);
    a.w = fmaf(g, a.w, xv.w);
    *reinterpret_cast<float4*>(outf + i) = a;
}

extern "C" __global__ __launch_bounds__(256)
void zero_buf(float* __restrict__ p)
{
    float4 z = {0.f,0.f,0.f,0.f};
    *reinterpret_cast<float4*>(p + ((size_t)blockIdx.x * 256 + threadIdx.x) * 4) = z;
}

extern "C" void kernel_launch(void* const* d_in, const int* in_sizes, int n_in,
                              void* d_out, int out_size, void* d_ws, size_t ws_size,
                              hipStream_t stream)
{
    (void)in_sizes; (void)n_in; (void)out_size;
    const float* x  = (const float*)d_in[0];
    const float* sf = (const float*)d_in[1];
    const float* Wq = (const float*)d_in[2];
    const float* bq = (const float*)d_in[3];
    const float* Wk = (const float*)d_in[4];
    const float* bk = (const float*)d_in[5];
    const float* Wv = (const float*)d_in[6];
    const float* bv = (const float*)d_in[7];
    const float* gm = (const float*)d_in[8];

    float* outf  = (float*)d_out;                       // [256][9216] f32
    float* attnf = outf + (size_t)256 * 9216;           // [9216][9216] f32

    char* ws = (char*)d_ws;
    u16*   xT    = (u16*)(ws);                          //  4,718,592
    u16*   sfT   = (u16*)(ws +  4718592);               //  4,718,592
    u16*   wqb   = (u16*)(ws +  9437184);               //     16,384
    u16*   wkb   = (u16*)(ws +  9453568);               //     16,384
    u16*   wvb   = (u16*)(ws +  9469952);               //    131,072
    u16*   qhb   = (u16*)(ws +  9601024);               //    589,824
    u16*   khb   = (u16*)(ws + 10190848);               //    589,824
    u16*   vbp   = (u16*)(ws + 10780672);               //  4,718,592
    float* pq    = (float*)(ws + 15499264);             //        288
    float* pk    = (float*)(ws + 15499552);             //        288
    float* S2    = (float*)(ws + 15499840);             //      4,096
    float* ksum  = (float*)(ws + 15503936);             //        128
    float* rinv  = (float*)(ws + 15504064);             //     36,864
    float* parts = (float*)(ws + 15540928);             // 8 × 9,437,184
    const size_t need = 15540928ull + 8ull * 9437184ull;

    const bool use_parts = (ws_size >= need);

    castT   <<<dim3(296),  dim3(256), 0, stream>>>(x, sf, Wq, Wk, Wv,
                                                   xT, sfT, wqb, wkb, wvb, S2, ksum);
    qk_gemm <<<dim3(72),   dim3(256), 0, stream>>>(xT, sfT, wqb, wkb, bq, bk,
                                                   qhb, khb, pq, pk);
    v_gemm  <<<dim3(576),  dim3(256), 0, stream>>>(xT, wvb, bv, vbp);
    s2k     <<<dim3(256),  dim3(256), 0, stream>>>(khb, S2, ksum);
    rowfin  <<<dim3(36),   dim3(256), 0, stream>>>(qhb, S2, ksum, pq, pk, rinv);
    if (!use_parts)
        zero_buf<<<dim3(2304), dim3(256), 0, stream>>>(outf);
    attn_main<<<dim3(1152), dim3(256), 0, stream>>>(qhb, khb, vbp, pq, pk, rinv,
                                                    use_parts ? parts : outf, attnf,
                                                    use_parts ? 0 : 1);
    epilogue <<<dim3(2304), dim3(256), 0, stream>>>(x, gm, parts,
                                                    use_parts ? 8 : 0, outf);
}

// Round 12
// 194.793 us; speedup vs baseline: 2.7248x; 1.0840x over previous
//
#include <hip/hip_runtime.h>
#include <hip/hip_bf16.h>

#define NN 9216      // W*H
#define CCH 256      // channels
#define PS2 268      // attn ps row stride (u16): dw stride 134 — conflict-free measured
#define CTS 268      // castT LDS row stride (u16)

typedef unsigned short u16;
typedef unsigned int   u32;
typedef __attribute__((ext_vector_type(8))) short bf16x8;   // 8 bf16 = 4 VGPRs
typedef __attribute__((ext_vector_type(4))) float f32x4;

static __device__ __forceinline__ u16 f2bf(float f){
    u32 u = __builtin_bit_cast(u32, f);
    u += 0x7fffu + ((u >> 16) & 1u);   // RNE; inputs finite
    return (u16)(u >> 16);
}
static __device__ __forceinline__ float bf2f(u16 h){
    u32 u = ((u32)h) << 16;
    return __builtin_bit_cast(float, u);
}

// ---------------- K0: cast+transpose x,sf -> [n][c] bf16; cast W's ----------
extern "C" __global__ __launch_bounds__(256)
void castT(const float* __restrict__ x, const float* __restrict__ sf,
           const float* __restrict__ Wq, const float* __restrict__ Wk,
           const float* __restrict__ Wv,
           u16* __restrict__ xT, u16* __restrict__ sfT,
           u16* __restrict__ wqb, u16* __restrict__ wkb, u16* __restrict__ wvb,
           float* __restrict__ S2, float* __restrict__ ksum)
{
    const int bid = blockIdx.x, t = threadIdx.x;
    if (bid < 288){
        __shared__ u16 ls[64 * CTS];
        const int isf = bid >= 144;
        const int n0 = (isf ? bid - 144 : bid) * 64;
        const float* src = isf ? sf : x;
        const int nl = t & 63;
        const int cg = t >> 6;          // 0..3
        for (int i = 0; i < 64; ++i){
            int c = cg * 64 + i;
            float v = src[(size_t)c * NN + n0 + nl];
            ls[nl * CTS + c] = f2bf(v);
        }
        __syncthreads();
        u16* dst = (isf ? sfT : xT) + (size_t)(n0 + nl) * 256 + cg * 64;
        const u16* lrow = &ls[nl * CTS + cg * 64];
        #pragma unroll
        for (int j = 0; j < 8; ++j){
            uint2 p = *reinterpret_cast<const uint2*>(lrow + j*8);
            uint2 q = *reinterpret_cast<const uint2*>(lrow + j*8 + 4);
            uint4 o; o.x = p.x; o.y = p.y; o.z = q.x; o.w = q.y;
            *reinterpret_cast<uint4*>(dst + j*8) = o;
        }
    } else {
        const int wb = bid - 288;       // 0..7
        if (wb == 0){
            #pragma unroll
            for (int k2 = 0; k2 < 4; ++k2) S2[t + 256*k2] = 0.f;
            if (t < 32) ksum[t] = 0.f;
        }
        for (int i = 0; i < 40; ++i){
            int idx = wb * 10240 + i * 256 + t;
            if (idx < 8192)        wqb[idx]         = f2bf(Wq[idx]);
            else if (idx < 16384)  wkb[idx - 8192]  = f2bf(Wk[idx - 8192]);
            else                   wvb[idx - 16384] = f2bf(Wv[idx - 16384]);
        }
    }
}

// ---------------- K1: merged q/k projection + v projection ------------------
// bids 0..71: qk (waves 0,1: q; 2,3: k) — center + sumsq partials
// bids 72..647: v -> vb bf16 [c][m]
extern "C" __global__ __launch_bounds__(256)
void proj_qkv(const u16* __restrict__ xT, const u16* __restrict__ sfT,
              const u16* __restrict__ wqb, const u16* __restrict__ wkb,
              const u16* __restrict__ wvb,
              const float* __restrict__ bq, const float* __restrict__ bk,
              const float* __restrict__ bv,
              u16* __restrict__ qhb, u16* __restrict__ khb, u16* __restrict__ vb,
              float* __restrict__ pq, float* __restrict__ pk)
{
    const int bid = blockIdx.x, t = threadIdx.x;
    const int w = t >> 6, l = t & 63, h = l >> 4, r = l & 15;
    if (bid < 72){
        __shared__ float wsum[2][2];
        const int isk = w >> 1, wn = w & 1;
        const int n0 = bid * 128 + wn * 64;
        const u16* B = isk ? xT : sfT;
        const u16* A = isk ? wkb : wqb;
        const float* bias = isk ? bk : bq;

        f32x4 acc[2][4];
        #pragma unroll
        for (int ot = 0; ot < 2; ++ot)
            #pragma unroll
            for (int nt = 0; nt < 4; ++nt) acc[ot][nt] = (f32x4){0.f,0.f,0.f,0.f};

        for (int ks = 0; ks < 8; ++ks){
            bf16x8 a0 = *reinterpret_cast<const bf16x8*>(A + (r     )*256 + ks*32 + 8*h);
            bf16x8 a1 = *reinterpret_cast<const bf16x8*>(A + (16 + r)*256 + ks*32 + 8*h);
            #pragma unroll
            for (int nt = 0; nt < 4; ++nt){
                bf16x8 b = *reinterpret_cast<const bf16x8*>(
                    B + (size_t)(n0 + nt*16 + r)*256 + ks*32 + 8*h);
                acc[0][nt] = __builtin_amdgcn_mfma_f32_16x16x32_bf16(a0, b, acc[0][nt], 0,0,0);
                acc[1][nt] = __builtin_amdgcn_mfma_f32_16x16x32_bf16(a1, b, acc[1][nt], 0,0,0);
            }
        }
        float bs[2][4];
        #pragma unroll
        for (int ot = 0; ot < 2; ++ot)
            #pragma unroll
            for (int g = 0; g < 4; ++g) bs[ot][g] = bias[ot*16 + 4*h + g];

        u16* outb = (isk ? khb : qhb);
        float ssl = 0.f;
        #pragma unroll
        for (int nt = 0; nt < 4; ++nt){
            float loc = 0.f;
            #pragma unroll
            for (int ot = 0; ot < 2; ++ot)
                #pragma unroll
                for (int g = 0; g < 4; ++g){
                    acc[ot][nt][g] += bs[ot][g];
                    loc += acc[ot][nt][g];
                }
            loc += __shfl_xor(loc, 16);
            loc += __shfl_xor(loc, 32);
            const float mn = loc * (1.f/32.f);
            u16* dstp = outb + (size_t)(n0 + nt*16 + r) * 32;
            #pragma unroll
            for (int ot = 0; ot < 2; ++ot)
                #pragma unroll
                for (int g = 0; g < 4; ++g){
                    u16 hb = f2bf(acc[ot][nt][g] - mn);
                    float rv = bf2f(hb);
                    ssl = fmaf(rv, rv, ssl);
                    dstp[ot*16 + 4*h + g] = hb;
                }
        }
        #pragma unroll
        for (int mask = 1; mask <= 32; mask <<= 1) ssl += __shfl_xor(ssl, mask);
        if (l == 0) wsum[isk][wn] = ssl;
        __syncthreads();
        if (t == 0) pq[bid] = wsum[0][0] + wsum[0][1];
        if (t == 1) pk[bid] = wsum[1][0] + wsum[1][1];
    } else {
        const int vbid = bid - 72;      // 0..575
        const int m0 = (vbid >> 2) * 64, c0 = (vbid & 3) * 64;

        f32x4 acc[4];
        #pragma unroll
        for (int nt = 0; nt < 4; ++nt) acc[nt] = (f32x4){0.f,0.f,0.f,0.f};

        for (int ks = 0; ks < 8; ++ks){
            bf16x8 a = *reinterpret_cast<const bf16x8*>(wvb + (c0 + w*16 + r)*256 + ks*32 + 8*h);
            #pragma unroll
            for (int nt = 0; nt < 4; ++nt){
                bf16x8 b = *reinterpret_cast<const bf16x8*>(
                    xT + (size_t)(m0 + nt*16 + r)*256 + ks*32 + 8*h);
                acc[nt] = __builtin_amdgcn_mfma_f32_16x16x32_bf16(a, b, acc[nt], 0,0,0);
            }
        }
        float bvv[4];
        #pragma unroll
        for (int g = 0; g < 4; ++g) bvv[g] = bv[c0 + w*16 + 4*h + g];
        #pragma unroll
        for (int nt = 0; nt < 4; ++nt)
            #pragma unroll
            for (int g = 0; g < 4; ++g)
                vb[(size_t)(c0 + w*16 + 4*h + g) * NN + m0 + nt*16 + r] =
                    f2bf(acc[nt][g] + bvv[g]);
    }
}

// ---------------- K2: S2 = K̂ᵀK̂, ksum = Σ k̂, invden scalar ----------------
extern "C" __global__ __launch_bounds__(256)
void s2k(const u16* __restrict__ khb, const float* __restrict__ pq,
         const float* __restrict__ pk,
         float* __restrict__ S2, float* __restrict__ ksum,
         float* __restrict__ invden)
{
    __shared__ float ks[36][33];
    const int t = threadIdx.x;
    const int m0 = blockIdx.x * 36;
    if (blockIdx.x == 0 && t == 0){
        float sq = 0.f, sk = 0.f;
        for (int i = 0; i < 72; ++i){ sq += pq[i]; sk += pk[i]; }
        invden[0] = rsqrtf(sq) * rsqrtf(sk);
    }
    if (t < 144){
        const int row = t >> 2, seg = (t & 3) * 8;
        bf16x8 v = *reinterpret_cast<const bf16x8*>(khb + (m0 + row) * 32 + seg);
        #pragma unroll
        for (int j = 0; j < 8; ++j)
            ks[row][seg + j] = bf2f((u16)v[j]);
    }
    __syncthreads();
    #pragma unroll
    for (int k2 = 0; k2 < 4; ++k2){
        const int task = t + 256 * k2;
        const int i = task >> 5, j = task & 31;
        float s = 0.f;
        for (int m = 0; m < 36; ++m)
            s = fmaf(ks[m][i], ks[m][j], s);
        atomicAdd(S2 + task, s);
    }
    if (t < 32){
        float s = 0.f;
        for (int m = 0; m < 36; ++m) s += ks[m][t];
        atomicAdd(ksum + t, s);
    }
}

// ---------------- K3: fused attention write + PV (round-8 structure,
// inline per-block rowsum) ----------
// grid 1152: nc = bid>>3 (64 n-rows), ms = bid&7 (1152 m-cols)
// 4 periods of 256 + 1 of 128, constant bounds.
extern "C" __global__ __launch_bounds__(256, 3)
void attn_main(const u16* __restrict__ qhb, const u16* __restrict__ khb,
               const u16* __restrict__ vb,
               const float* __restrict__ S2, const float* __restrict__ ksum,
               const float* __restrict__ invden,
               float* __restrict__ outdst, float* __restrict__ attnf,
               int use_atomic)
{
    __shared__ u16 ps[64 * PS2];
    __shared__ float s2s[1024];
    __shared__ float kss[32];
    __shared__ float rsl[64];
    const int bid = blockIdx.x;
    const int nc = bid >> 3, ms = bid & 7;
    const int t = threadIdx.x, w = t >> 6, l = t & 63, h = l >> 4, r = l & 15;
    const int n0 = nc * 64, mbase = ms * 1152;

    const float inv_den = invden[0];

    // ---- inline rowfin: rsl[row] for this block's 64 rows ----
    #pragma unroll
    for (int k2 = 0; k2 < 4; ++k2) s2s[t + 256*k2] = S2[t + 256*k2];
    if (t < 32) kss[t] = ksum[t];
    __syncthreads();
    {
        const int rrow = t >> 2, rp = (t & 3) * 8;
        float q32[32];
        #pragma unroll
        for (int s8 = 0; s8 < 4; ++s8){
            bf16x8 v = *reinterpret_cast<const bf16x8*>(qhb + (size_t)(n0 + rrow)*32 + s8*8);
            #pragma unroll
            for (int j = 0; j < 8; ++j) q32[s8*8 + j] = bf2f((u16)v[j]);
        }
        float d1 = 0.f, qd = 0.f;
        #pragma unroll
        for (int o = 0; o < 8; ++o){
            const int oo = rp + o;
            float s = 0.f;
            #pragma unroll
            for (int j = 0; j < 32; ++j) s = fmaf(s2s[oo*32 + j], q32[j], s);
            qd = fmaf(q32[oo], s, qd);
            d1 = fmaf(q32[oo], kss[oo], d1);
        }
        float comb = fmaf(0.5f * qd, inv_den, d1);    // d1 + 0.5*qd*d
        comb += __shfl_xor(comb, 1);
        comb += __shfl_xor(comb, 2);
        if ((t & 3) == 0) rsl[rrow] = 1.f / fmaf(comb, inv_den, 9216.f);
    }

    bf16x8 qf[4];
    #pragma unroll
    for (int nt = 0; nt < 4; ++nt)
        qf[nt] = *reinterpret_cast<const bf16x8*>(qhb + (size_t)(n0 + nt*16 + r)*32 + 8*h);

    // acc[ct][nt] holds D[n][c]: n = n0+nt*16+4h+g, c = w*64+ct*16+r  (swapped PV)
    f32x4 acc[4][4];
    #pragma unroll
    for (int ct = 0; ct < 4; ++ct)
        #pragma unroll
        for (int nt = 0; nt < 4; ++nt)
            acc[ct][nt] = (f32x4){0.f,0.f,0.f,0.f};

    // QK -> Taylor exp (unnormalized) -> ps[bf16]
    #define STAGE_TILE(M0S, K64) \
        _Pragma("unroll") \
        for (int k64 = 0; k64 < (K64); ++k64){ \
            bf16x8 kf = *reinterpret_cast<const bf16x8*>( \
                khb + (size_t)((M0S) + k64*64 + w*16 + r)*32 + 8*h); \
            _Pragma("unroll") \
            for (int nt = 0; nt < 4; ++nt){ \
                f32x4 z = {0.f,0.f,0.f,0.f}; \
                f32x4 e = __builtin_amdgcn_mfma_f32_16x16x32_bf16(qf[nt], kf, z, 0,0,0); \
                _Pragma("unroll") \
                for (int g = 0; g < 4; ++g){ \
                    float ep = e[g] * inv_den; \
                    float pt = fmaf(ep, fmaf(0.5f, ep, 1.f), 1.f); \
                    ps[(nt*16 + 4*h + g) * PS2 + k64*64 + w*16 + r] = f2bf(pt); \
                } \
            } \
        }

    // attention rows -> global f32 (nontemporal)
    #define WRITE_TILE(M0S, SPAN) \
        _Pragma("unroll 4") \
        for (int j = 0; j < 16; ++j){ \
            const int row = w + 4*j; \
            const float rv = rsl[row]; \
            if ((SPAN) == 256 || l < 32){ \
                ushort4 u = *reinterpret_cast<const ushort4*>(&ps[row * PS2 + l*4]); \
                f32x4 f4; \
                f4[0] = bf2f(u.x)*rv; f4[1] = bf2f(u.y)*rv; \
                f4[2] = bf2f(u.z)*rv; f4[3] = bf2f(u.w)*rv; \
                __builtin_nontemporal_store(f4, reinterpret_cast<f32x4*>( \
                    attnf + (size_t)(n0 + row) * NN + (M0S) + l*4)); \
            } \
        }

    // PV (swapped): acc += P(rows n) x V(rows c)
    #define PV_TILE(M0S, KSL) \
        _Pragma("unroll 2") \
        for (int ksl = 0; ksl < (KSL); ++ksl){ \
            bf16x8 av[4]; \
            _Pragma("unroll") \
            for (int ct = 0; ct < 4; ++ct) \
                av[ct] = *reinterpret_cast<const bf16x8*>( \
                    vb + (size_t)(w*64 + ct*16 + r) * NN + (M0S) + ksl*32 + 8*h); \
            bf16x8 bv2[4]; \
            _Pragma("unroll") \
            for (int nt = 0; nt < 4; ++nt) \
                bv2[nt] = *reinterpret_cast<const bf16x8*>( \
                    &ps[(nt*16 + r) * PS2 + ksl*32 + 8*h]); \
            __builtin_amdgcn_s_setprio(1); \
            _Pragma("unroll") \
            for (int ct = 0; ct < 4; ++ct) \
                _Pragma("unroll") \
                for (int nt = 0; nt < 4; ++nt) \
                    acc[ct][nt] = __builtin_amdgcn_mfma_f32_16x16x32_bf16( \
                        bv2[nt], av[ct], acc[ct][nt], 0,0,0); \
            __builtin_amdgcn_s_setprio(0); \
        }

    for (int p = 0; p < 4; ++p){
        const int m0 = mbase + p * 256;
        STAGE_TILE(m0, 4)
        __syncthreads();
        WRITE_TILE(m0, 256)
        PV_TILE(m0, 8)
        __syncthreads();
    }
    {
        const int m0 = mbase + 1024;
        STAGE_TILE(m0, 2)
        __syncthreads();
        WRITE_TILE(m0, 128)
        PV_TILE(m0, 4)
        __syncthreads();
    }
    #undef STAGE_TILE
    #undef WRITE_TILE
    #undef PV_TILE

    if (!use_atomic){
        float* dst = outdst + (size_t)ms * (CCH * NN);
        #pragma unroll
        for (int ct = 0; ct < 4; ++ct)
            #pragma unroll
            for (int nt = 0; nt < 4; ++nt){
                f32x4 o;
                #pragma unroll
                for (int g = 0; g < 4; ++g)
                    o[g] = acc[ct][nt][g] * rsl[nt*16 + 4*h + g];
                __builtin_nontemporal_store(o, reinterpret_cast<f32x4*>(
                    dst + (size_t)(w*64 + ct*16 + r) * NN + n0 + nt*16 + 4*h));
            }
    } else {
        #pragma unroll
        for (int ct = 0; ct < 4; ++ct)
            #pragma unroll
            for (int nt = 0; nt < 4; ++nt)
                #pragma unroll
                for (int g = 0; g < 4; ++g)
                    atomicAdd(outdst + (size_t)(w*64 + ct*16 + r) * NN + n0 + nt*16 + 4*h + g,
                              acc[ct][nt][g] * rsl[nt*16 + 4*h + g]);
    }
}

// ---------------- K4: out = gamma*(sum partials) + x ----------------
extern "C" __global__ __launch_bounds__(256)
void epilogue(const float* __restrict__ x, const float* __restrict__ gm,
              const float* __restrict__ parts, int nparts,
              float* __restrict__ outf)
{
    const float g = gm[0];
    const size_t i = ((size_t)blockIdx.x * 256 + threadIdx.x) * 4;
    float4 a;
    if (nparts > 0){
        a.x = a.y = a.z = a.w = 0.f;
        for (int s = 0; s < nparts; ++s){
            float4 p = *reinterpret_cast<const float4*>(parts + (size_t)s * (CCH*NN) + i);
            a.x += p.x; a.y += p.y; a.z += p.z; a.w += p.w;
        }
    } else {
        a = *reinterpret_cast<float4*>(outf + i);
    }
    float4 xv = *reinterpret_cast<const float4*>(x + i);
    a.x = fmaf(g, a.x, xv.x);
    a.y = fmaf(g, a.y, xv.y);
    a.z = fmaf(g, a.z, xv.z);
    a.w = fmaf(g, a.w, xv.w);
    *reinterpret_cast<float4*>(outf + i) = a;
}

extern "C" __global__ __launch_bounds__(256)
void zero_buf(float* __restrict__ p)
{
    float4 z = {0.f,0.f,0.f,0.f};
    *reinterpret_cast<float4*>(p + ((size_t)blockIdx.x * 256 + threadIdx.x) * 4) = z;
}

extern "C" void kernel_launch(void* const* d_in, const int* in_sizes, int n_in,
                              void* d_out, int out_size, void* d_ws, size_t ws_size,
                              hipStream_t stream)
{
    (void)in_sizes; (void)n_in; (void)out_size;
    const float* x  = (const float*)d_in[0];
    const float* sf = (const float*)d_in[1];
    const float* Wq = (const float*)d_in[2];
    const float* bq = (const float*)d_in[3];
    const float* Wk = (const float*)d_in[4];
    const float* bk = (const float*)d_in[5];
    const float* Wv = (const float*)d_in[6];
    const float* bv = (const float*)d_in[7];
    const float* gm = (const float*)d_in[8];

    float* outf  = (float*)d_out;                       // [256][9216] f32
    float* attnf = outf + (size_t)256 * 9216;           // [9216][9216] f32

    char* ws = (char*)d_ws;
    u16*   xT    = (u16*)(ws);                          //  4,718,592
    u16*   sfT   = (u16*)(ws +  4718592);               //  4,718,592
    u16*   wqb   = (u16*)(ws +  9437184);               //     16,384
    u16*   wkb   = (u16*)(ws +  9453568);               //     16,384
    u16*   wvb   = (u16*)(ws +  9469952);               //    131,072
    u16*   qhb   = (u16*)(ws +  9601024);               //    589,824
    u16*   khb   = (u16*)(ws + 10190848);               //    589,824
    u16*   vbp   = (u16*)(ws + 10780672);               //  4,718,592
    float* pq    = (float*)(ws + 15499264);             //        288
    float* pk    = (float*)(ws + 15499552);             //        288
    float* S2    = (float*)(ws + 15499840);             //      4,096
    float* ksum  = (float*)(ws + 15503936);             //        128
    float* invd  = (float*)(ws + 15504064);             //          4
    float* parts = (float*)(ws + 15540928);             // 8 × 9,437,184
    const size_t need = 15540928ull + 8ull * 9437184ull;

    const bool use_parts = (ws_size >= need);

    castT    <<<dim3(296),  dim3(256), 0, stream>>>(x, sf, Wq, Wk, Wv,
                                                    xT, sfT, wqb, wkb, wvb, S2, ksum);
    proj_qkv <<<dim3(648),  dim3(256), 0, stream>>>(xT, sfT, wqb, wkb, wvb,
                                                    bq, bk, bv, qhb, khb, vbp, pq, pk);
    s2k      <<<dim3(256),  dim3(256), 0, stream>>>(khb, pq, pk, S2, ksum, invd);
    if (!use_parts)
        zero_buf<<<dim3(2304), dim3(256), 0, stream>>>(outf);
    attn_main<<<dim3(1152), dim3(256), 0, stream>>>(qhb, khb, vbp, S2, ksum, invd,
                                                    use_parts ? parts : outf, attnf,
                                                    use_parts ? 0 : 1);
    epilogue <<<dim3(2304), dim3(256), 0, stream>>>(x, gm, parts,
                                                    use_parts ? 8 : 0, outf);
}